// Round 10
// baseline (95.835 us; speedup 1.0000x reference)
//
#include <hip/hip_runtime.h>

#define CIN    256
#define COUT   256
#define PTOT   4096
#define BN     64     // pixels per block; block = 256o x 64p, 8 waves
#define BK     32
#define KSTEPS 8

typedef __attribute__((ext_vector_type(8)))  short bfrag;
typedef __attribute__((ext_vector_type(16))) float f32x16;

union U4F { unsigned int u[4]; bfrag f; };

// Hardware RNE f32->bf16 pair convert (bit-validated R8/R9: absmax identical).
__device__ __forceinline__ unsigned int cvt_pk(float lo, float hi) {
    unsigned int r;
    asm("v_cvt_pk_bf16_f32 %0, %1, %2" : "=v"(r) : "v"(lo), "v"(hi));
    return r;
}

__device__ __forceinline__ f32x16 zero16() {
    f32x16 v;
    #pragma unroll
    for (int i = 0; i < 16; ++i) v[i] = 0.0f;
    return v;
}

// Counted barrier (R7-proven safe): LDS visibility only; global prefetch
// loads stay in flight across it.
__device__ __forceinline__ void lds_barrier() {
    asm volatile("s_waitcnt lgkmcnt(0)" ::: "memory");
    __builtin_amdgcn_s_barrier();
    asm volatile("" ::: "memory");
}

// A (weight) read DIRECT from global: rows are k-contiguous = exactly the
// MFMA A-frag layout, and the 256KB/sample slice is L2-resident via the XCD
// swizzle. LDS carries only B (the true transpose). Both operands use the
// identical (fr, kh+j) -> k index math, so any hw k-permutation cancels.
__global__ __launch_bounds__(512, 6)
void selconv_adirect(const float* __restrict__ x,
                     const int*   __restrict__ classes,
                     const float* __restrict__ weight,
                     const float* __restrict__ bias,
                     float*       __restrict__ out)
{
    // B: u32 k-pair rows [16][64 px] -> 4 KB per buffer (low16=even k, high16=odd k)
    __shared__ __align__(16) unsigned int Bs[2][(BK / 2) * BN];
    __shared__ float bias_s[COUT];     // total 9.2 KB; occupancy capped by (512,6)

    // XCD-aware bijective swizzle (2048 % 8 == 0), sample-major per XCD:
    // weight slice L2-resident; BM=256 -> each x byte used by exactly 1 block.
    const int b     = blockIdx.x;
    const int xcd   = b & 7;
    const int local = b >> 3;                  // 0..255
    const int n     = xcd * 4 + (local >> 6);  // 0..31
    const int p0    = (local & 63) * BN;

    const int tid  = threadIdx.x;
    const int lane = tid & 63;
    const int wid  = tid >> 6;                // 0..7 -> o-rows [32*wid, 32*wid+32)
    const int fr   = lane & 31;               // row/col within 32x32 frag
    const int kh   = (lane >> 5) * 8;         // 8 consecutive k per lane

    const int cls = classes[n];
    const float* Wn = weight + (size_t)cls * (COUT * CIN);
    const float* Xn = x   + (size_t)n * (CIN * PTOT) + p0;
    float*       On = out + (size_t)n * (COUT * PTOT) + p0;

    if (tid < COUT) bias_s[tid] = bias[cls * COUT + tid];

    const float* Ap = Wn + (size_t)(wid * 32 + fr) * CIN + kh;

    // B staging map: thread -> k-pair row (tid>>5), 2 pixels (tid&31)*2.
    // Per wave-instr: 2 rows x 256B contiguous -> coalesced. LDS b64 write at
    // 8B stride -> 4 slots/bank (b64 floor). Frag reads: bank = fr -> 32
    // distinct banks, 2 lanes/bank (free, m136).
    const int b_kp = tid >> 5;            // 0..15
    const int b_p2 = (tid & 31) * 2;      // 0..62

    float2 E0, O0, E1, O1;                // two named prefetch sets (rule #20)

    auto loadB0 = [&](int t) {
        const int kr = t * BK + 2 * b_kp;
        E0 = *(const float2*)(Xn + (size_t)kr       * PTOT + b_p2);
        O0 = *(const float2*)(Xn + (size_t)(kr + 1) * PTOT + b_p2);
    };
    auto loadB1 = [&](int t) {
        const int kr = t * BK + 2 * b_kp;
        E1 = *(const float2*)(Xn + (size_t)kr       * PTOT + b_p2);
        O1 = *(const float2*)(Xn + (size_t)(kr + 1) * PTOT + b_p2);
    };
    auto writeB = [&](int buf, const float2& E, const float2& O) {
        uint2 wv;
        wv.x = cvt_pk(E.x, O.x);
        wv.y = cvt_pk(E.y, O.y);
        *(uint2*)(&Bs[buf][b_kp * BN + b_p2]) = wv;
    };

    f32x16 acc0 = zero16(), acc1 = zero16();

    auto step = [&](int t, int buf) {
        const int k0 = t * BK;
        // A direct from L2: 4 x dwordx4 off one base with literal offsets.
        const float4 a0 = *(const float4*)(Ap + k0);
        const float4 a1 = *(const float4*)(Ap + k0 + 4);
        const float4 a2 = *(const float4*)(Ap + k0 + 16);
        const float4 a3 = *(const float4*)(Ap + k0 + 20);
        const unsigned int* Bb = Bs[buf];
        #pragma unroll
        for (int s = 0; s < 2; ++s) {
            const int kp0 = s * 8 + (kh >> 1);   // 4 consecutive k-pair rows
            U4F u0, u1;
            u0.u[0] = Bb[(kp0 + 0) * BN + fr];
            u0.u[1] = Bb[(kp0 + 1) * BN + fr];
            u0.u[2] = Bb[(kp0 + 2) * BN + fr];
            u0.u[3] = Bb[(kp0 + 3) * BN + fr];
            u1.u[0] = Bb[(kp0 + 0) * BN + fr + 32];
            u1.u[1] = Bb[(kp0 + 1) * BN + fr + 32];
            u1.u[2] = Bb[(kp0 + 2) * BN + fr + 32];
            u1.u[3] = Bb[(kp0 + 3) * BN + fr + 32];
            U4F af;
            if (s == 0) {
                af.u[0] = cvt_pk(a0.x, a0.y);
                af.u[1] = cvt_pk(a0.z, a0.w);
                af.u[2] = cvt_pk(a1.x, a1.y);
                af.u[3] = cvt_pk(a1.z, a1.w);
            } else {
                af.u[0] = cvt_pk(a2.x, a2.y);
                af.u[1] = cvt_pk(a2.z, a2.w);
                af.u[2] = cvt_pk(a3.x, a3.y);
                af.u[3] = cvt_pk(a3.z, a3.w);
            }
            acc0 = __builtin_amdgcn_mfma_f32_32x32x16_bf16(af.f, u0.f, acc0, 0, 0, 0);
            acc1 = __builtin_amdgcn_mfma_f32_32x32x16_bf16(af.f, u1.f, acc1, 0, 0, 0);
        }
    };

    // ---- 2-deep B pipeline; 1 barrier per K-step; loads survive barriers ----
    loadB0(0);
    loadB1(1);
    writeB(0, E0, O0);
    lds_barrier();

    #pragma unroll
    for (int t = 0; t < KSTEPS; t += 2) {
        if (t + 2 < KSTEPS) loadB0(t + 2);
        step(t, 0);
        writeB(1, E1, O1);                 // tile t+1 (regs loaded one step ago)
        lds_barrier();
        if (t + 3 < KSTEPS) loadB1(t + 3);
        step(t + 1, 1);
        if (t + 2 < KSTEPS) { writeB(0, E0, O0); lds_barrier(); }
    }

    // epilogue: D col = lane&31, row = (reg&3) + 8*(reg>>2) + 4*(lane>>5)
    const int col = lane & 31;
    const int rh  = (lane >> 5) * 4;
    #pragma unroll
    for (int r = 0; r < 16; ++r) {
        const int row = (r & 3) + 8 * (r >> 2) + rh;
        const int o   = wid * 32 + row;
        On[(size_t)o * PTOT + col]      = acc0[r] + bias_s[o];
        On[(size_t)o * PTOT + col + 32] = acc1[r] + bias_s[o];
    }
}

extern "C" void kernel_launch(void* const* d_in, const int* in_sizes, int n_in,
                              void* d_out, int out_size, void* d_ws, size_t ws_size,
                              hipStream_t stream) {
    const float* x       = (const float*)d_in[0];
    const int*   classes = (const int*)d_in[1];
    const float* weight  = (const float*)d_in[2];
    const float* bias    = (const float*)d_in[3];
    float*       out     = (float*)d_out;

    const int grid = 32 * (PTOT / BN);   // 2048 blocks of 512 threads
    selconv_adirect<<<grid, 512, 0, stream>>>(x, classes, weight, bias, out);
}